// Round 8
// baseline (466.080 us; speedup 1.0000x reference)
//
#include <hip/hip_runtime.h>
#include <hip/hip_bf16.h>

#define D_IN    2880
#define HDIM    256
#define NSPEC   4
#define NATOMS  16384
#define NSTRUCT 64
#define NT1     45     // D_IN/64
#define NT2     4      // HDIM/64

typedef __attribute__((ext_vector_type(4))) float f32x4;
typedef __attribute__((ext_vector_type(8))) short s16x8;
typedef __attribute__((ext_vector_type(4))) unsigned short u16x4;

__device__ __forceinline__ short f2bf(float f) {
    return (short)__builtin_bit_cast(unsigned short, __float2bfloat16(f));
}

// Pack weights [S][RDIM][256] f32 -> MFMA-fragment-ordered bf16:
// wp[(s*(RDIM/64)+kt)*16384 + (hq*2+kk)*512 + lane*8 + e]
//   = bf16( w[s][kt*64 + kk*32 + (lane>>4)*8 + e][hq*16 + (lane&15)] )
template<int RDIM>
__global__ void pack_w(const float* __restrict__ w, unsigned short* __restrict__ wp) {
    __shared__ unsigned short T[64][264];
    const int kt = blockIdx.x, s = blockIdx.y;
    const int t = threadIdx.x;
    const float* src = w + ((size_t)s * RDIM + kt * 64) * HDIM;
#pragma unroll
    for (int i = 0; i < 16; ++i) {
        const int row = i * 4 + (t >> 6);
        const int c4 = (t & 63) * 4;
        f32x4 v = *(const f32x4*)(src + (size_t)row * HDIM + c4);
        u16x4 u;
        u[0] = (unsigned short)f2bf(v[0]); u[1] = (unsigned short)f2bf(v[1]);
        u[2] = (unsigned short)f2bf(v[2]); u[3] = (unsigned short)f2bf(v[3]);
        *(u16x4*)&T[row][c4] = u;
    }
    __syncthreads();
    unsigned short* dst = wp + ((size_t)s * (RDIM / 64) + kt) * 16384;
    const int l = t & 63;
#pragma unroll
    for (int it = 0; it < 8; ++it) {
        const int c = (t >> 6) + it * 4;          // 0..31  (= hq*2+kk)
        const int hq = c >> 1, kk = c & 1;
        s16x8 vv;
#pragma unroll
        for (int e = 0; e < 8; ++e)
            vv[e] = (short)T[kk * 32 + (l >> 4) * 8 + e][hq * 16 + (l & 15)];
        *(s16x8*)(dst + (size_t)c * 512 + l * 8) = vv;
    }
}

__device__ __forceinline__ int hswz(int row, int colbyte) {   // H1 tile: 512B rows
    return row * 512 + (colbyte ^ ((row & 7) << 4));
}

// Barrier-free fused MLP.
// 512 blocks x 256 threads (4 waves). Block = 32 atoms x 256 cols.
// Wave wv (0..3) owns all 32 rows x cols [wv*64, wv*64+64): fully independent
// K-loop: A-fragments straight from global (fp32->bf16 in reg), B-fragments
// from packed L2-resident weights. NO LDS / NO barrier in the K-loop.
// One barrier only at the H1 handoff (GEMM2 k-dim couples the col-quarters).
__global__ __launch_bounds__(256, 2)
void fused_mlp(const float* __restrict__ feat,
               const unsigned short* __restrict__ w1p,
               const float* __restrict__ b1,
               const unsigned short* __restrict__ w2p,
               const float* __restrict__ b2,
               const float* __restrict__ w_last,
               const float* __restrict__ b_last,
               const float* __restrict__ comp_w,
               const int* __restrict__ sidx,
               float* __restrict__ out)
{
    __shared__ __align__(16) char Hb[32 * 512];    // 32 x 256 bf16, swizzled
    __shared__ float ered[4][32];

    const int tid  = threadIdx.x;
    const int lane = tid & 63;
    const int wv   = tid >> 6;            // 0..3: cols wv*64 .. wv*64+63
    const int lrow = lane & 15, lq = lane >> 4;
    const int g    = blockIdx.x;
    const int s    = (g & 7) >> 1;                       // species pinned to XCD pair
    const int idx  = ((g >> 3) << 1) | (g & 1);          // 0..127 (32-row tiles)
    const int row0 = s * (NATOMS / NSPEC) + idx * 32;

    const float* Ag = feat + (size_t)row0 * D_IN;
    const unsigned short* B1 = w1p + (size_t)s * NT1 * 16384;
    const unsigned short* B2 = w2p + (size_t)s * NT2 * 16384;

    f32x4 acc[2][4];
#pragma unroll
    for (int i = 0; i < 2; ++i)
#pragma unroll
        for (int j = 0; j < 4; ++j) acc[i][j] = (f32x4){0.f, 0.f, 0.f, 0.f};

    // ---------------- GEMM1: 45 K-steps, barrier-free ----------------
    for (int kt = 0; kt < NT1; ++kt) {
        // B fragments: 8 x 1KB coalesced loads (L2-resident, species-pinned)
        s16x8 bf[4][2];
#pragma unroll
        for (int j = 0; j < 4; ++j)
#pragma unroll
            for (int kk = 0; kk < 2; ++kk)
                bf[j][kk] = *(const s16x8*)(B1 + ((size_t)kt * 32 + (wv * 4 + j) * 2 + kk) * 512 + lane * 8);
        // A fragments straight from global: frag(i,kk) = 16 rows x 128B/row
        s16x8 af[2][2];
#pragma unroll
        for (int i = 0; i < 2; ++i)
#pragma unroll
            for (int kk = 0; kk < 2; ++kk) {
                const float* ap = Ag + (size_t)(i * 16 + lrow) * D_IN + kt * 64 + kk * 32 + lq * 8;
                f32x4 v0 = *(const f32x4*)ap;
                f32x4 v1 = *(const f32x4*)(ap + 4);
                s16x8 w;
                w[0]=f2bf(v0[0]); w[1]=f2bf(v0[1]); w[2]=f2bf(v0[2]); w[3]=f2bf(v0[3]);
                w[4]=f2bf(v1[0]); w[5]=f2bf(v1[1]); w[6]=f2bf(v1[2]); w[7]=f2bf(v1[3]);
                af[i][kk] = w;
            }
#pragma unroll
        for (int kk = 0; kk < 2; ++kk)
#pragma unroll
            for (int i = 0; i < 2; ++i)
#pragma unroll
                for (int j = 0; j < 4; ++j)
                    acc[i][j] = __builtin_amdgcn_mfma_f32_16x16x32_bf16(af[i][kk], bf[j][kk], acc[i][j], 0, 0, 0);
    }

    // ---------------- bias + silu -> H1 (swizzled LDS), one barrier ----------------
    {
        const float* b1s = b1 + s * HDIM;
#pragma unroll
        for (int j = 0; j < 4; ++j) {
            const int col = wv * 64 + j * 16 + lrow;
            const float bias = b1s[col];
#pragma unroll
            for (int i = 0; i < 2; ++i)
#pragma unroll
                for (int r = 0; r < 4; ++r) {
                    float x = acc[i][j][r] + bias;
                    float sg = 1.0f / (1.0f + __expf(-x));
                    const int row = i * 16 + lq * 4 + r;
                    *(unsigned short*)(&Hb[0] + hswz(row, col * 2)) = (unsigned short)f2bf(x * sg);
                }
        }
    }
#pragma unroll
    for (int i = 0; i < 2; ++i)
#pragma unroll
        for (int j = 0; j < 4; ++j) acc[i][j] = (f32x4){0.f, 0.f, 0.f, 0.f};
    __syncthreads();

    // ---------------- GEMM2: 4 K-steps, H1 read-only ----------------
#pragma unroll
    for (int kt = 0; kt < NT2; ++kt) {
        s16x8 bf[4][2];
#pragma unroll
        for (int j = 0; j < 4; ++j)
#pragma unroll
            for (int kk = 0; kk < 2; ++kk)
                bf[j][kk] = *(const s16x8*)(B2 + ((size_t)kt * 32 + (wv * 4 + j) * 2 + kk) * 512 + lane * 8);
        s16x8 af[2][2];
#pragma unroll
        for (int i = 0; i < 2; ++i)
#pragma unroll
            for (int kk = 0; kk < 2; ++kk)
                af[i][kk] = *(const s16x8*)(&Hb[0] + hswz(i * 16 + lrow, (kt * 64 + kk * 32 + lq * 8) * 2));
#pragma unroll
        for (int kk = 0; kk < 2; ++kk)
#pragma unroll
            for (int i = 0; i < 2; ++i)
#pragma unroll
                for (int j = 0; j < 4; ++j)
                    acc[i][j] = __builtin_amdgcn_mfma_f32_16x16x32_bf16(af[i][kk], bf[j][kk], acc[i][j], 0, 0, 0);
    }

    // ---------------- epilogue: e = silu(h2) . w_last ; reduce ; atomic ----------------
    {
        const float* b2s = b2 + s * HDIM;
        const float* wls = w_last + s * HDIM;
        float p[8];
#pragma unroll
        for (int t = 0; t < 8; ++t) p[t] = 0.f;
#pragma unroll
        for (int j = 0; j < 4; ++j) {
            const int col = wv * 64 + j * 16 + lrow;
            const float bias = b2s[col];
            const float wl = wls[col];
#pragma unroll
            for (int i = 0; i < 2; ++i)
#pragma unroll
                for (int r = 0; r < 4; ++r) {
                    float x = acc[i][j][r] + bias;
                    float sg = 1.0f / (1.0f + __expf(-x));
                    p[i * 4 + r] += x * sg * wl;
                }
        }
        // sum across the 16 lanes (lrow) holding different cols
#pragma unroll
        for (int d = 1; d < 16; d <<= 1)
#pragma unroll
            for (int t = 0; t < 8; ++t)
                p[t] += __shfl_xor(p[t], d, 64);
        if (lrow == 0) {
#pragma unroll
            for (int i = 0; i < 2; ++i)
#pragma unroll
                for (int r = 0; r < 4; ++r)
                    ered[wv][i * 16 + lq * 4 + r] = p[i * 4 + r];
        }
        __syncthreads();
        if (tid < 32) {
            float e = ered[0][tid] + ered[1][tid] + ered[2][tid] + ered[3][tid]
                    + b_last[s] + comp_w[s];
            atomicAdd(&out[sidx[row0 + tid]], e);
        }
    }
}

extern "C" void kernel_launch(void* const* d_in, const int* in_sizes, int n_in,
                              void* d_out, int out_size, void* d_ws, size_t ws_size,
                              hipStream_t stream) {
    (void)in_sizes; (void)n_in; (void)out_size; (void)ws_size;
    const float* feat   = (const float*)d_in[0];
    const float* w1     = (const float*)d_in[1];
    const float* b1     = (const float*)d_in[2];
    const float* w2     = (const float*)d_in[3];
    const float* b2     = (const float*)d_in[4];
    const float* w_last = (const float*)d_in[5];
    const float* b_last = (const float*)d_in[6];
    const float* comp_w = (const float*)d_in[7];
    const int*   sidx   = (const int*)d_in[8];
    float* out = (float*)d_out;

    unsigned short* w1p = (unsigned short*)d_ws;                   // 4*45*16384 shorts
    unsigned short* w2p = w1p + (size_t)NSPEC * NT1 * 16384;       // 4*4*16384 shorts

    hipMemsetAsync(d_out, 0, NSTRUCT * sizeof(float), stream);
    pack_w<D_IN><<<dim3(NT1, NSPEC), 256, 0, stream>>>(w1, w1p);
    pack_w<HDIM><<<dim3(NT2, NSPEC), 256, 0, stream>>>(w2, w2p);
    fused_mlp<<<512, 256, 0, stream>>>(feat, w1p, b1, w2p, b2,
                                       w_last, b_last, comp_w, sidx, out);
}